// Round 1
// baseline (5857.314 us; speedup 1.0000x reference)
//
#include <hip/hip_runtime.h>
#include <hip/hip_bf16.h>
#include <math.h>

#define D16   16
#define NC    64      // channels C
#define NH    8       // heads
#define CHD   128     // (C/H)*D = 8*16
#define NLAY  2
#define CEXP  256     // C*FM
#define NK    8       // rotors
#define SEQ   1024
#define BATCH 2
#define VOCAB 32000

// ---- Cl(3,1) sign helpers (mirror the Python cayley construction) ----------
__device__ __forceinline__ float gp_sign(int a, int b) {
    int t = a >> 1, tot = 0;
    while (t) { tot += __popc(t & b); t >>= 1; }
    int neg = tot & 1;
    if ((a & b) & 8) neg ^= 1;   // METRIC[3] = -1 (e4^2 = -1)
    return neg ? -1.f : 1.f;
}
__device__ __forceinline__ float rev_sign(int j) {
    int g = __popc(j);
    return ((g * (g - 1) / 2) & 1) ? -1.f : 1.f;
}

// ---- embed gather + rotary bivector PE (sandwich R x R~) -------------------
__global__ void embed_pe_kernel(const int* __restrict__ tok,
                                const float* __restrict__ embed,
                                float* __restrict__ x) {
    int idx = blockIdx.x * blockDim.x + threadIdx.x;      // (b*L+l)*C + c
    if (idx >= BATCH * SEQ * NC) return;
    int c  = idx & (NC - 1);
    int bl = idx / NC;
    int l  = bl & (SEQ - 1);
    int t  = tok[bl];

    const float* e = embed + ((size_t)t * NC + c) * D16;
    float v[D16];
#pragma unroll
    for (int j = 0; j < D16; j++) v[j] = e[j];

    float freq = powf(10000.f, -(float)c / (float)NC);
    float theta = (float)l * freq;
    float sn, cs;
    sincosf(theta, &sn, &cs);

    float tmp[D16], out[D16];
#pragma unroll
    for (int k = 0; k < D16; k++)
        tmp[k] = cs * v[k] + sn * gp_sign(3, 3 ^ k) * v[3 ^ k];
#pragma unroll
    for (int k = 0; k < D16; k++)
        out[k] = cs * tmp[k] - sn * gp_sign(k ^ 3, 3) * tmp[k ^ 3];

    float* xp = x + (size_t)idx * D16;
#pragma unroll
    for (int j = 0; j < D16; j++) xp[j] = out[j];
}

// ---- CliffordLayerNorm: rms over (C,D) per (b,l), per-channel gain ---------
__global__ void cln_kernel(const float* __restrict__ x,
                           const float* __restrict__ g,
                           float* __restrict__ xn) {
    int bl = blockIdx.x;
    const float* xr = x + (size_t)bl * NC * D16;
    __shared__ float red[256];
    float s = 0.f;
    for (int i = threadIdx.x; i < NC * D16; i += 256) { float v = xr[i]; s += v * v; }
    red[threadIdx.x] = s; __syncthreads();
    for (int st = 128; st > 0; st >>= 1) {
        if (threadIdx.x < st) red[threadIdx.x] += red[threadIdx.x + st];
        __syncthreads();
    }
    float inv = 1.f / sqrtf(red[0] * (1.f / 1024.f) + 1e-6f);
    for (int i = threadIdx.x; i < NC * D16; i += 256) {
        int c = i >> 4;
        xn[(size_t)bl * 1024 + i] = xr[i] * inv * g[c];
    }
}

// ---- fused q/k/v projection: [64x64] @ [64x16] per (b,l) -------------------
__global__ void qkv_kernel(const float* __restrict__ xn,
                           const float* __restrict__ wq,
                           const float* __restrict__ wk,
                           const float* __restrict__ wv,
                           float* __restrict__ q, float* __restrict__ k,
                           float* __restrict__ v) {
    int bl = blockIdx.x;
    __shared__ float xs[NC * D16];
    for (int i = threadIdx.x; i < NC * D16; i += 256) xs[i] = xn[(size_t)bl * 1024 + i];
    __syncthreads();
    int d  = threadIdx.x & 15;
    int og = threadIdx.x >> 4;
    const float* Ws[3] = { wq, wk, wv };
    float* Os[3] = { q, k, v };
#pragma unroll
    for (int m = 0; m < 3; m++) {
        const float* W = Ws[m];
        float* O = Os[m];
#pragma unroll
        for (int oo = 0; oo < 4; oo++) {
            int o = og * 4 + oo;
            float acc = 0.f;
#pragma unroll
            for (int c = 0; c < NC; c++) acc += W[o * NC + c] * xs[c * D16 + d];
            O[(size_t)bl * 1024 + o * D16 + d] = acc;
        }
    }
}

// ---- fused attention row: scores -> softmax -> AV --------------------------
__global__ void attn_kernel(const float* __restrict__ q,
                            const float* __restrict__ k,
                            const float* __restrict__ v,
                            float* __restrict__ o) {
    int l  = blockIdx.x;
    int bh = blockIdx.y;
    int b  = bh / NH, h = bh % NH;
    __shared__ float qs[CHD];
    __shared__ float sc[SEQ];
    __shared__ float red[256];
    int t = threadIdx.x;
    const float scale = 0.088388347648318447f;   // 1/sqrt(128)

    if (t < CHD) {
        int dd = t & 15;
        qs[t] = q[(size_t)(b * SEQ + l) * 1024 + h * CHD + t] * gp_sign(dd, dd) * scale;
    }
    __syncthreads();

    for (int m = t; m <= l; m += 256) {
        const float* kr = k + (size_t)(b * SEQ + m) * 1024 + h * CHD;
        float s = 0.f;
#pragma unroll
        for (int j = 0; j < CHD; j++) s += qs[j] * kr[j];
        sc[m] = s;
    }
    __syncthreads();

    float mx = -INFINITY;
    for (int m = t; m <= l; m += 256) mx = fmaxf(mx, sc[m]);
    red[t] = mx; __syncthreads();
    for (int st = 128; st > 0; st >>= 1) {
        if (t < st) red[t] = fmaxf(red[t], red[t + st]);
        __syncthreads();
    }
    mx = red[0]; __syncthreads();

    float sm = 0.f;
    for (int m = t; m <= l; m += 256) { float e = expf(sc[m] - mx); sc[m] = e; sm += e; }
    red[t] = sm; __syncthreads();
    for (int st = 128; st > 0; st >>= 1) {
        if (t < st) red[t] += red[t + st];
        __syncthreads();
    }
    float denom = red[0]; __syncthreads();

    int j = t & 127, half = t >> 7;
    float acc = 0.f;
    for (int m = half; m <= l; m += 2)
        acc += sc[m] * v[(size_t)(b * SEQ + m) * 1024 + h * CHD + j];
    red[t] = acc; __syncthreads();
    if (t < CHD)
        o[(size_t)(b * SEQ + l) * 1024 + h * CHD + j] = (red[t] + red[t + 128]) / denom;
}

// ---- wo projection + residual add ------------------------------------------
__global__ void proj_add_kernel(const float* __restrict__ in,
                                const float* __restrict__ W,
                                float* __restrict__ x) {
    int bl = blockIdx.x;
    __shared__ float xs[NC * D16];
    for (int i = threadIdx.x; i < NC * D16; i += 256) xs[i] = in[(size_t)bl * 1024 + i];
    __syncthreads();
    int d  = threadIdx.x & 15;
    int og = threadIdx.x >> 4;
#pragma unroll
    for (int oo = 0; oo < 4; oo++) {
        int o = og * 4 + oo;
        float acc = 0.f;
#pragma unroll
        for (int c = 0; c < NC; c++) acc += W[o * NC + c] * xs[c * D16 + d];
        x[(size_t)bl * 1024 + o * D16 + d] += acc;
    }
}

// ---- FFN up: [256x64] @ [64x16] per (b,l) ----------------------------------
__global__ void ffn_up_kernel(const float* __restrict__ xn,
                              const float* __restrict__ W,
                              float* __restrict__ h) {
    int bl = blockIdx.x;
    __shared__ float xs[NC * D16];
    for (int i = threadIdx.x; i < NC * D16; i += 256) xs[i] = xn[(size_t)bl * 1024 + i];
    __syncthreads();
    int e = threadIdx.x;
    float acc[D16];
#pragma unroll
    for (int dd = 0; dd < D16; dd++) acc[dd] = 0.f;
    for (int c = 0; c < NC; c++) {
        float w = W[e * NC + c];
#pragma unroll
        for (int dd = 0; dd < D16; dd++) acc[dd] += w * xs[c * D16 + dd];
    }
    float* hp = h + (size_t)bl * (CEXP * D16) + e * D16;
#pragma unroll
    for (int dd = 0; dd < D16; dd++) hp[dd] = acc[dd];
}

// ---- per-layer mixed rotor sandwich matrix Tmix[16][16] --------------------
__global__ void tmix_kernel(const float* __restrict__ rotor_biv,  // [NL,K,6]
                            const float* __restrict__ mixw,       // [NL,K]
                            float* __restrict__ Tmix) {           // [NL,16,16]
    int lay = blockIdx.x;
    __shared__ float rot[NK][D16];
    __shared__ float w[NK];
    int t = threadIdx.x;
    if (t < NK) {
        const int BIV[6] = { 3, 5, 6, 9, 10, 12 };
        float r[D16];
#pragma unroll
        for (int j = 0; j < D16; j++) r[j] = 0.f;
        r[0] = 1.f;
        float nrm = 1.f;
        for (int i = 0; i < 6; i++) {
            float bv = rotor_biv[(lay * NK + t) * 6 + i];
            r[BIV[i]] = bv; nrm += bv * bv;
        }
        nrm = sqrtf(nrm);
        for (int j = 0; j < D16; j++) rot[t][j] = r[j] / nrm;
    }
    if (t == 0) {
        float mx = -INFINITY;
        for (int kk = 0; kk < NK; kk++) mx = fmaxf(mx, mixw[lay * NK + kk]);
        float s = 0.f, e[NK];
        for (int kk = 0; kk < NK; kk++) { e[kk] = expf(mixw[lay * NK + kk] - mx); s += e[kk]; }
        for (int kk = 0; kk < NK; kk++) w[kk] = e[kk] / s;
    }
    __syncthreads();
    int j = t >> 4, p = t & 15;
    float acc = 0.f;
    for (int kk = 0; kk < NK; kk++) {
        float tk = 0.f;
        for (int i = 0; i < D16; i++) {
            int n = i ^ j ^ p;
            float rn = rot[kk][n] * rev_sign(n);          // rrev
            tk += rot[kk][i] * rn * gp_sign(i, j) * gp_sign(i ^ j, n);
        }
        acc += w[kk] * tk;
    }
    Tmix[lay * 256 + t] = acc;
}

// ---- apply Tmix + gelu (tanh approx), in place on h ------------------------
__global__ void rotor_gelu_kernel(float* __restrict__ h,
                                  const float* __restrict__ Tmix) {
    int idx = blockIdx.x * blockDim.x + threadIdx.x;     // (b*L)*CE + e
    __shared__ float Ts[256];
    if (threadIdx.x < 256) Ts[threadIdx.x] = Tmix[threadIdx.x];
    __syncthreads();
    if (idx >= BATCH * SEQ * CEXP) return;
    float* hp = h + (size_t)idx * D16;
    float hv[D16];
#pragma unroll
    for (int j = 0; j < D16; j++) hv[j] = hp[j];
    const float kA = 0.7978845608028654f;                // sqrt(2/pi)
#pragma unroll
    for (int p = 0; p < D16; p++) {
        float s = 0.f;
#pragma unroll
        for (int j = 0; j < D16; j++) s += hv[j] * Ts[j * 16 + p];
        float g = 0.5f * s * (1.f + tanhf(kA * (s + 0.044715f * s * s * s)));
        hp[p] = g;
    }
}

// ---- FFN down + residual ---------------------------------------------------
__global__ void ffn_down_kernel(const float* __restrict__ h,
                                const float* __restrict__ W,   // [C][CE]
                                float* __restrict__ x) {
    int bl = blockIdx.x;
    __shared__ float hs[CEXP * D16];
    for (int i = threadIdx.x; i < CEXP * D16; i += 256) hs[i] = h[(size_t)bl * (CEXP * D16) + i];
    __syncthreads();
    int d = threadIdx.x & 15;
#pragma unroll
    for (int i = 0; i < 4; i++) {
        int c = (threadIdx.x >> 4) + i * 16;
        float acc = 0.f;
        for (int e = 0; e < CEXP; e++) acc += W[c * CEXP + e] * hs[e * D16 + d];
        x[(size_t)bl * 1024 + c * D16 + d] += acc;
    }
}

// ---- final norm + blade gate + grade-0 extract -----------------------------
__global__ void g0_kernel(const float* __restrict__ x,
                          const float* __restrict__ g,
                          const float* __restrict__ sel,
                          float* __restrict__ g0) {
    int bl = blockIdx.x;
    const float* xr = x + (size_t)bl * 1024;
    __shared__ float red[256];
    float s = 0.f;
    for (int i = threadIdx.x; i < 1024; i += 256) { float v = xr[i]; s += v * v; }
    red[threadIdx.x] = s; __syncthreads();
    for (int st = 128; st > 0; st >>= 1) {
        if (threadIdx.x < st) red[threadIdx.x] += red[threadIdx.x + st];
        __syncthreads();
    }
    float inv = 1.f / sqrtf(red[0] * (1.f / 1024.f) + 1e-6f);
    if (threadIdx.x < NC) {
        int c = threadIdx.x;
        float gate = 1.f / (1.f + expf(-sel[c * D16]));
        g0[(size_t)bl * NC + c] = xr[c * D16] * inv * g[c] * gate;
    }
}

// ---- head_w transpose ------------------------------------------------------
__global__ void transpose_hw(const float* __restrict__ hw, float* __restrict__ hwT) {
    int idx = blockIdx.x * blockDim.x + threadIdx.x;
    if (idx >= VOCAB * NC) return;
    int v = idx / NC, c = idx & (NC - 1);
    hwT[(size_t)c * VOCAB + v] = hw[idx];
}

// ---- head GEMM: [2048,64] @ [64,32000] + bias ------------------------------
__global__ void head_kernel(const float* __restrict__ g0,
                            const float* __restrict__ hwT,
                            const float* __restrict__ hb,
                            float* __restrict__ out) {
    int vb = blockIdx.x * 256;
    int rb = blockIdx.y * 32;
    __shared__ float gs[32][NC];
    int t = threadIdx.x;
    for (int i = t; i < 32 * NC; i += 256) {
        int r = i >> 6, c = i & 63;
        gs[r][c] = g0[(size_t)(rb + r) * NC + c];
    }
    __syncthreads();
    int v = vb + t;
    float acc[32];
#pragma unroll
    for (int r = 0; r < 32; r++) acc[r] = 0.f;
    for (int c = 0; c < NC; c++) {
        float w = hwT[(size_t)c * VOCAB + v];
#pragma unroll
        for (int r = 0; r < 32; r++) acc[r] += gs[r][c] * w;
    }
    float bb = hb[v];
#pragma unroll
    for (int r = 0; r < 32; r++) out[(size_t)(rb + r) * VOCAB + v] = acc[r] + bb;
}

extern "C" void kernel_launch(void* const* d_in, const int* in_sizes, int n_in,
                              void* d_out, int out_size, void* d_ws, size_t ws_size,
                              hipStream_t stream) {
    (void)in_sizes; (void)n_in; (void)out_size; (void)ws_size;
    const int*   tok      = (const int*)  d_in[0];
    const float* embed    = (const float*)d_in[1];
    const float* ln1_g    = (const float*)d_in[2];
    const float* ln2_g    = (const float*)d_in[3];
    const float* wq       = (const float*)d_in[4];
    const float* wk       = (const float*)d_in[5];
    const float* wv       = (const float*)d_in[6];
    const float* wo       = (const float*)d_in[7];
    const float* ffn_up   = (const float*)d_in[8];
    const float* ffn_down = (const float*)d_in[9];
    const float* rotor    = (const float*)d_in[10];
    const float* mixw     = (const float*)d_in[11];
    const float* out_ln_g = (const float*)d_in[12];
    const float* sel      = (const float*)d_in[13];
    const float* head_w   = (const float*)d_in[14];
    const float* head_b   = (const float*)d_in[15];
    float* out = (float*)d_out;

    float* ws  = (float*)d_ws;
    float* x    = ws;                 // 2,097,152
    float* xn   = x    + 2097152;     // 2,097,152
    float* q    = xn   + 2097152;
    float* k    = q    + 2097152;
    float* v    = k    + 2097152;
    float* o    = v    + 2097152;
    float* h    = o    + 2097152;     // 8,388,608
    float* Tmx  = h    + 8388608;     // 512
    float* g0   = Tmx  + 512;         // 131,072
    float* hwT  = g0   + 131072;      // 2,048,000

    embed_pe_kernel<<<(BATCH * SEQ * NC + 255) / 256, 256, 0, stream>>>(tok, embed, x);
    tmix_kernel<<<NLAY, 256, 0, stream>>>(rotor, mixw, Tmx);
    transpose_hw<<<(VOCAB * NC + 255) / 256, 256, 0, stream>>>(head_w, hwT);

    for (int l = 0; l < NLAY; l++) {
        cln_kernel<<<BATCH * SEQ, 256, 0, stream>>>(x, ln1_g + l * NC, xn);
        qkv_kernel<<<BATCH * SEQ, 256, 0, stream>>>(xn, wq + l * NC * NC, wk + l * NC * NC,
                                                    wv + l * NC * NC, q, k, v);
        dim3 ag(SEQ, BATCH * NH);
        attn_kernel<<<ag, 256, 0, stream>>>(q, k, v, o);
        proj_add_kernel<<<BATCH * SEQ, 256, 0, stream>>>(o, wo + l * NC * NC, x);
        cln_kernel<<<BATCH * SEQ, 256, 0, stream>>>(x, ln2_g + l * NC, xn);
        ffn_up_kernel<<<BATCH * SEQ, 256, 0, stream>>>(xn, ffn_up + l * CEXP * NC, h);
        rotor_gelu_kernel<<<(BATCH * SEQ * CEXP + 255) / 256, 256, 0, stream>>>(h, Tmx + l * 256);
        ffn_down_kernel<<<BATCH * SEQ, 256, 0, stream>>>(h, ffn_down + l * NC * CEXP, x);
    }

    g0_kernel<<<BATCH * SEQ, 256, 0, stream>>>(x, out_ln_g, sel, g0);
    dim3 hg(VOCAB / 256, BATCH * SEQ / 32);
    head_kernel<<<hg, 256, 0, stream>>>(g0, hwT, head_b, out);
}

// Round 2
// 989.216 us; speedup vs baseline: 5.9212x; 5.9212x over previous
//
#include <hip/hip_runtime.h>
#include <hip/hip_bf16.h>
#include <math.h>

#define D16   16
#define NC    64      // channels C
#define NH    8       // heads
#define CHD   128     // (C/H)*D = 8*16
#define NLAY  2
#define CEXP  256     // C*FM
#define NK    8       // rotors
#define SEQ   1024
#define BATCH 2
#define VOCAB 32000

// ---- Cl(3,1) sign helpers (mirror the Python cayley construction) ----------
__device__ __forceinline__ float gp_sign(int a, int b) {
    int t = a >> 1, tot = 0;
    while (t) { tot += __popc(t & b); t >>= 1; }
    int neg = tot & 1;
    if ((a & b) & 8) neg ^= 1;   // METRIC[3] = -1 (e4^2 = -1)
    return neg ? -1.f : 1.f;
}
__device__ __forceinline__ float rev_sign(int j) {
    int g = __popc(j);
    return ((g * (g - 1) / 2) & 1) ? -1.f : 1.f;
}

// ---- embed gather + rotary bivector PE (sandwich R x R~) -------------------
__global__ void embed_pe_kernel(const int* __restrict__ tok,
                                const float* __restrict__ embed,
                                float* __restrict__ x) {
    int idx = blockIdx.x * blockDim.x + threadIdx.x;      // (b*L+l)*C + c
    if (idx >= BATCH * SEQ * NC) return;
    int c  = idx & (NC - 1);
    int bl = idx / NC;
    int l  = bl & (SEQ - 1);
    int t  = tok[bl];

    const float* e = embed + ((size_t)t * NC + c) * D16;
    float v[D16];
#pragma unroll
    for (int j = 0; j < D16; j++) v[j] = e[j];

    float freq = powf(10000.f, -(float)c / (float)NC);
    float theta = (float)l * freq;
    float sn, cs;
    sincosf(theta, &sn, &cs);

    float tmp[D16], out[D16];
#pragma unroll
    for (int k = 0; k < D16; k++)
        tmp[k] = cs * v[k] + sn * gp_sign(3, 3 ^ k) * v[3 ^ k];
#pragma unroll
    for (int k = 0; k < D16; k++)
        out[k] = cs * tmp[k] - sn * gp_sign(k ^ 3, 3) * tmp[k ^ 3];

    float* xp = x + (size_t)idx * D16;
#pragma unroll
    for (int j = 0; j < D16; j++) xp[j] = out[j];
}

// ---- CliffordLayerNorm: rms over (C,D) per (b,l), per-channel gain ---------
__global__ void cln_kernel(const float* __restrict__ x,
                           const float* __restrict__ g,
                           float* __restrict__ xn) {
    int bl = blockIdx.x;
    const float* xr = x + (size_t)bl * NC * D16;
    __shared__ float red[256];
    float s = 0.f;
    for (int i = threadIdx.x; i < NC * D16; i += 256) { float v = xr[i]; s += v * v; }
    red[threadIdx.x] = s; __syncthreads();
    for (int st = 128; st > 0; st >>= 1) {
        if (threadIdx.x < st) red[threadIdx.x] += red[threadIdx.x + st];
        __syncthreads();
    }
    float inv = 1.f / sqrtf(red[0] * (1.f / 1024.f) + 1e-6f);
    for (int i = threadIdx.x; i < NC * D16; i += 256) {
        int c = i >> 4;
        xn[(size_t)bl * 1024 + i] = xr[i] * inv * g[c];
    }
}

// ---- fused q/k/v projection: [64x64] @ [64x16] per (b,l) -------------------
__global__ void qkv_kernel(const float* __restrict__ xn,
                           const float* __restrict__ wq,
                           const float* __restrict__ wk,
                           const float* __restrict__ wv,
                           float* __restrict__ q, float* __restrict__ k,
                           float* __restrict__ v) {
    int bl = blockIdx.x;
    __shared__ float xs[NC * D16];
    for (int i = threadIdx.x; i < NC * D16; i += 256) xs[i] = xn[(size_t)bl * 1024 + i];
    __syncthreads();
    int d  = threadIdx.x & 15;
    int og = threadIdx.x >> 4;
    const float* Ws[3] = { wq, wk, wv };
    float* Os[3] = { q, k, v };
#pragma unroll
    for (int m = 0; m < 3; m++) {
        const float* W = Ws[m];
        float* O = Os[m];
#pragma unroll
        for (int oo = 0; oo < 4; oo++) {
            int o = og * 4 + oo;
            float acc = 0.f;
#pragma unroll
            for (int c = 0; c < NC; c++) acc += W[o * NC + c] * xs[c * D16 + d];
            O[(size_t)bl * 1024 + o * D16 + d] = acc;
        }
    }
}

// ---- flash attention: Q-tile 32, K/V-tile 64, paired causal tasks ----------
// grid (16, B*H); block 256. Thread (rg=t>>4, cg=t&15):
//   scores: rows {2rg,2rg+1} x cols {4cg..4cg+3}
//   PV:     rows {2rg,2rg+1} x j in {4cg..4cg+3} u {64+4cg..64+4cg+3}
__global__ __launch_bounds__(256) void flash_attn_kernel(
        const float* __restrict__ q, const float* __restrict__ k,
        const float* __restrict__ v, float* __restrict__ o) {
    int slot = blockIdx.x;
    int bh = blockIdx.y;
    int b = bh >> 3, h = bh & 7;
    int t = threadIdx.x;
    int rg = t >> 4, cg = t & 15;
    int jv_s = t & 31;                 // staging chunk col (fixed per thread)

    __shared__ float4 qs4[32 * 32];    // [row][chunk]  (plain)
    __shared__ float4 kv4[64 * 32];    // K swizzled / V plain (reused)
    __shared__ float4 ps4[32 * 17];    // P, row stride 17 float4

    const float scale = 0.088388347648318447f;  // 1/sqrt(128)

    // gmet*scale for this thread's staging chunk (Q staging)
    float4 gm;
    {
        int d0 = (jv_s * 4) & 15;
        gm.x = gp_sign(d0, d0) * scale;
        gm.y = gp_sign(d0 + 1, d0 + 1) * scale;
        gm.z = gp_sign(d0 + 2, d0 + 2) * scale;
        gm.w = gp_sign(d0 + 3, d0 + 3) * scale;
    }

    for (int task = 0; task < 2; task++) {
        int qi = (task == 0) ? slot : (31 - slot);
        int T = (qi >> 1) + 1;

        __syncthreads();   // protect qs/kv from previous task's readers
        // ---- stage Q tile (pre-scaled by gmet*scale) ----
        {
            const float* qb = q + (size_t)(b * SEQ + qi * 32) * 1024 + h * CHD;
#pragma unroll
            for (int it = 0; it < 4; it++) {
                int row = it * 8 + (t >> 5);
                float4 val = *(const float4*)(qb + (size_t)row * 1024 + jv_s * 4);
                float4 sv; sv.x = val.x * gm.x; sv.y = val.y * gm.y;
                sv.z = val.z * gm.z; sv.w = val.w * gm.w;
                qs4[row * 32 + jv_s] = sv;
            }
        }

        float m_run[2] = { -1e30f, -1e30f };
        float l_run[2] = { 0.f, 0.f };
        float oa[2][2][4];
#pragma unroll
        for (int a = 0; a < 2; a++)
#pragma unroll
            for (int bb = 0; bb < 2; bb++)
#pragma unroll
                for (int e = 0; e < 4; e++) oa[a][bb][e] = 0.f;

        for (int kt = 0; kt < T; kt++) {
            __syncthreads();  // Q staged / prev PV done
            // ---- stage K tile (swizzled) ----
            {
                const float* kb = k + (size_t)(b * SEQ + kt * 64) * 1024 + h * CHD;
#pragma unroll
                for (int it = 0; it < 8; it++) {
                    int row = it * 8 + (t >> 5);
                    float4 val = *(const float4*)(kb + (size_t)row * 1024 + jv_s * 4);
                    kv4[row * 32 + (jv_s ^ ((row >> 2) & 7))] = val;
                }
            }
            __syncthreads();

            // ---- scores: acc[2][4] ----
            float acc[2][4];
#pragma unroll
            for (int ri = 0; ri < 2; ri++)
#pragma unroll
                for (int ci = 0; ci < 4; ci++) acc[ri][ci] = 0.f;
            int swz = cg & 7;
#pragma unroll 4
            for (int jv = 0; jv < 32; jv++) {
                float4 q0 = qs4[(rg * 2) * 32 + jv];
                float4 q1 = qs4[(rg * 2 + 1) * 32 + jv];
#pragma unroll
                for (int ci = 0; ci < 4; ci++) {
                    float4 kk = kv4[(cg * 4 + ci) * 32 + (jv ^ swz)];
                    acc[0][ci] += q0.x * kk.x + q0.y * kk.y + q0.z * kk.z + q0.w * kk.w;
                    acc[1][ci] += q1.x * kk.x + q1.y * kk.y + q1.z * kk.z + q1.w * kk.w;
                }
            }

            // ---- causal mask on diagonal tile ----
            if (kt == T - 1) {
                int mb = kt * 64 + cg * 4;
                int rb = qi * 32 + rg * 2;
#pragma unroll
                for (int ri = 0; ri < 2; ri++)
#pragma unroll
                    for (int ci = 0; ci < 4; ci++)
                        if (mb + ci > rb + ri) acc[ri][ci] = -1e30f;
            }

            // ---- online softmax, write P ----
#pragma unroll
            for (int ri = 0; ri < 2; ri++) {
                float tm = fmaxf(fmaxf(acc[ri][0], acc[ri][1]),
                                 fmaxf(acc[ri][2], acc[ri][3]));
                tm = fmaxf(tm, __shfl_xor(tm, 1, 16));
                tm = fmaxf(tm, __shfl_xor(tm, 2, 16));
                tm = fmaxf(tm, __shfl_xor(tm, 4, 16));
                tm = fmaxf(tm, __shfl_xor(tm, 8, 16));
                float mnew = fmaxf(m_run[ri], tm);
                float corr = __expf(m_run[ri] - mnew);
                float p0 = __expf(acc[ri][0] - mnew);
                float p1 = __expf(acc[ri][1] - mnew);
                float p2 = __expf(acc[ri][2] - mnew);
                float p3 = __expf(acc[ri][3] - mnew);
                float ts = p0 + p1 + p2 + p3;
                ts += __shfl_xor(ts, 1, 16);
                ts += __shfl_xor(ts, 2, 16);
                ts += __shfl_xor(ts, 4, 16);
                ts += __shfl_xor(ts, 8, 16);
                l_run[ri] = l_run[ri] * corr + ts;
                m_run[ri] = mnew;
#pragma unroll
                for (int bb = 0; bb < 2; bb++)
#pragma unroll
                    for (int e = 0; e < 4; e++) oa[ri][bb][e] *= corr;
                float4 pv; pv.x = p0; pv.y = p1; pv.z = p2; pv.w = p3;
                ps4[(rg * 2 + ri) * 17 + cg] = pv;
            }
            __syncthreads();

            // ---- stage V tile (plain) over kv ----
            {
                const float* vb = v + (size_t)(b * SEQ + kt * 64) * 1024 + h * CHD;
#pragma unroll
                for (int it = 0; it < 8; it++) {
                    int row = it * 8 + (t >> 5);
                    float4 val = *(const float4*)(vb + (size_t)row * 1024 + jv_s * 4);
                    kv4[row * 32 + jv_s] = val;
                }
            }
            __syncthreads();

            // ---- PV accumulate ----
#pragma unroll 2
            for (int mv = 0; mv < 16; mv++) {
                float4 p0 = ps4[(rg * 2) * 17 + mv];
                float4 p1 = ps4[(rg * 2 + 1) * 17 + mv];
                float pa[4] = { p0.x, p0.y, p0.z, p0.w };
                float pb[4] = { p1.x, p1.y, p1.z, p1.w };
#pragma unroll
                for (int e = 0; e < 4; e++) {
                    int m = mv * 4 + e;
                    float4 va = kv4[m * 32 + cg];
                    float4 vb4 = kv4[m * 32 + 16 + cg];
                    oa[0][0][0] += pa[e] * va.x;  oa[0][0][1] += pa[e] * va.y;
                    oa[0][0][2] += pa[e] * va.z;  oa[0][0][3] += pa[e] * va.w;
                    oa[0][1][0] += pa[e] * vb4.x; oa[0][1][1] += pa[e] * vb4.y;
                    oa[0][1][2] += pa[e] * vb4.z; oa[0][1][3] += pa[e] * vb4.w;
                    oa[1][0][0] += pb[e] * va.x;  oa[1][0][1] += pb[e] * va.y;
                    oa[1][0][2] += pb[e] * va.z;  oa[1][0][3] += pb[e] * va.w;
                    oa[1][1][0] += pb[e] * vb4.x; oa[1][1][1] += pb[e] * vb4.y;
                    oa[1][1][2] += pb[e] * vb4.z; oa[1][1][3] += pb[e] * vb4.w;
                }
            }
        }

        // ---- write output ----
#pragma unroll
        for (int ri = 0; ri < 2; ri++) {
            float inv = 1.f / l_run[ri];
            size_t row = (size_t)(b * SEQ + qi * 32 + rg * 2 + ri) * 1024 + h * CHD;
            float4 w0; w0.x = oa[ri][0][0] * inv; w0.y = oa[ri][0][1] * inv;
            w0.z = oa[ri][0][2] * inv; w0.w = oa[ri][0][3] * inv;
            float4 w1; w1.x = oa[ri][1][0] * inv; w1.y = oa[ri][1][1] * inv;
            w1.z = oa[ri][1][2] * inv; w1.w = oa[ri][1][3] * inv;
            *(float4*)(o + row + cg * 4)      = w0;
            *(float4*)(o + row + 64 + cg * 4) = w1;
        }
    }
}

// ---- wo projection + residual add ------------------------------------------
__global__ void proj_add_kernel(const float* __restrict__ in,
                                const float* __restrict__ W,
                                float* __restrict__ x) {
    int bl = blockIdx.x;
    __shared__ float xs[NC * D16];
    for (int i = threadIdx.x; i < NC * D16; i += 256) xs[i] = in[(size_t)bl * 1024 + i];
    __syncthreads();
    int d  = threadIdx.x & 15;
    int og = threadIdx.x >> 4;
#pragma unroll
    for (int oo = 0; oo < 4; oo++) {
        int o = og * 4 + oo;
        float acc = 0.f;
#pragma unroll
        for (int c = 0; c < NC; c++) acc += W[o * NC + c] * xs[c * D16 + d];
        x[(size_t)bl * 1024 + o * D16 + d] += acc;
    }
}

// ---- FFN up + rotor mix + gelu fused ---------------------------------------
__global__ void ffn_up_gelu_kernel(const float* __restrict__ xn,
                                   const float* __restrict__ W,
                                   const float* __restrict__ Tmix,
                                   float* __restrict__ h) {
    int bl = blockIdx.x;
    __shared__ float xs[NC * D16];
    __shared__ float Ts[256];
    for (int i = threadIdx.x; i < NC * D16; i += 256) xs[i] = xn[(size_t)bl * 1024 + i];
    Ts[threadIdx.x] = Tmix[threadIdx.x];
    __syncthreads();
    int e = threadIdx.x;
    float acc[D16];
#pragma unroll
    for (int dd = 0; dd < D16; dd++) acc[dd] = 0.f;
    for (int c = 0; c < NC; c++) {
        float w = W[e * NC + c];
#pragma unroll
        for (int dd = 0; dd < D16; dd++) acc[dd] += w * xs[c * D16 + dd];
    }
    float* hp = h + (size_t)bl * (CEXP * D16) + e * D16;
    const float kA = 0.7978845608028654f;
#pragma unroll
    for (int p = 0; p < D16; p++) {
        float s = 0.f;
#pragma unroll
        for (int j = 0; j < D16; j++) s += acc[j] * Ts[j * 16 + p];
        float g = 0.5f * s * (1.f + tanhf(kA * (s + 0.044715f * s * s * s)));
        hp[p] = g;
    }
}

// ---- per-layer mixed rotor sandwich matrix Tmix[16][16] --------------------
__global__ void tmix_kernel(const float* __restrict__ rotor_biv,  // [NL,K,6]
                            const float* __restrict__ mixw,       // [NL,K]
                            float* __restrict__ Tmix) {           // [NL,16,16]
    int lay = blockIdx.x;
    __shared__ float rot[NK][D16];
    __shared__ float w[NK];
    int t = threadIdx.x;
    if (t < NK) {
        const int BIV[6] = { 3, 5, 6, 9, 10, 12 };
        float r[D16];
#pragma unroll
        for (int j = 0; j < D16; j++) r[j] = 0.f;
        r[0] = 1.f;
        float nrm = 1.f;
        for (int i = 0; i < 6; i++) {
            float bv = rotor_biv[(lay * NK + t) * 6 + i];
            r[BIV[i]] = bv; nrm += bv * bv;
        }
        nrm = sqrtf(nrm);
        for (int j = 0; j < D16; j++) rot[t][j] = r[j] / nrm;
    }
    if (t == 0) {
        float mx = -INFINITY;
        for (int kk = 0; kk < NK; kk++) mx = fmaxf(mx, mixw[lay * NK + kk]);
        float s = 0.f, e[NK];
        for (int kk = 0; kk < NK; kk++) { e[kk] = expf(mixw[lay * NK + kk] - mx); s += e[kk]; }
        for (int kk = 0; kk < NK; kk++) w[kk] = e[kk] / s;
    }
    __syncthreads();
    int j = t >> 4, p = t & 15;
    float acc = 0.f;
    for (int kk = 0; kk < NK; kk++) {
        float tk = 0.f;
        for (int i = 0; i < D16; i++) {
            int n = i ^ j ^ p;
            float rn = rot[kk][n] * rev_sign(n);          // rrev
            tk += rot[kk][i] * rn * gp_sign(i, j) * gp_sign(i ^ j, n);
        }
        acc += w[kk] * tk;
    }
    Tmix[lay * 256 + t] = acc;
}

// ---- FFN down + residual ---------------------------------------------------
__global__ void ffn_down_kernel(const float* __restrict__ h,
                                const float* __restrict__ W,   // [C][CE]
                                float* __restrict__ x) {
    int bl = blockIdx.x;
    __shared__ float hs[CEXP * D16];
    for (int i = threadIdx.x; i < CEXP * D16; i += 256) hs[i] = h[(size_t)bl * (CEXP * D16) + i];
    __syncthreads();
    int d = threadIdx.x & 15;
#pragma unroll
    for (int i = 0; i < 4; i++) {
        int c = (threadIdx.x >> 4) + i * 16;
        float acc = 0.f;
        for (int e = 0; e < CEXP; e++) acc += W[c * CEXP + e] * hs[e * D16 + d];
        x[(size_t)bl * 1024 + c * D16 + d] += acc;
    }
}

// ---- final norm + blade gate + grade-0 extract -----------------------------
__global__ void g0_kernel(const float* __restrict__ x,
                          const float* __restrict__ g,
                          const float* __restrict__ sel,
                          float* __restrict__ g0) {
    int bl = blockIdx.x;
    const float* xr = x + (size_t)bl * 1024;
    __shared__ float red[256];
    float s = 0.f;
    for (int i = threadIdx.x; i < 1024; i += 256) { float v = xr[i]; s += v * v; }
    red[threadIdx.x] = s; __syncthreads();
    for (int st = 128; st > 0; st >>= 1) {
        if (threadIdx.x < st) red[threadIdx.x] += red[threadIdx.x + st];
        __syncthreads();
    }
    float inv = 1.f / sqrtf(red[0] * (1.f / 1024.f) + 1e-6f);
    if (threadIdx.x < NC) {
        int c = threadIdx.x;
        float gate = 1.f / (1.f + expf(-sel[c * D16]));
        g0[(size_t)bl * NC + c] = xr[c * D16] * inv * g[c] * gate;
    }
}

// ---- head_w transpose ------------------------------------------------------
__global__ void transpose_hw(const float* __restrict__ hw, float* __restrict__ hwT) {
    int idx = blockIdx.x * blockDim.x + threadIdx.x;
    if (idx >= VOCAB * NC) return;
    int v = idx / NC, c = idx & (NC - 1);
    hwT[(size_t)c * VOCAB + v] = hw[idx];
}

// ---- head GEMM: [2048,64] @ [64,32000] + bias ------------------------------
__global__ void head_kernel(const float* __restrict__ g0,
                            const float* __restrict__ hwT,
                            const float* __restrict__ hb,
                            float* __restrict__ out) {
    int vb = blockIdx.x * 256;
    int rb = blockIdx.y * 32;
    __shared__ float gs[32][NC];
    int t = threadIdx.x;
    for (int i = t; i < 32 * NC; i += 256) {
        int r = i >> 6, c = i & 63;
        gs[r][c] = g0[(size_t)(rb + r) * NC + c];
    }
    __syncthreads();
    int v = vb + t;
    float acc[32];
#pragma unroll
    for (int r = 0; r < 32; r++) acc[r] = 0.f;
    for (int c = 0; c < NC; c++) {
        float w = hwT[(size_t)c * VOCAB + v];
#pragma unroll
        for (int r = 0; r < 32; r++) acc[r] += gs[r][c] * w;
    }
    float bb = hb[v];
#pragma unroll
    for (int r = 0; r < 32; r++) out[(size_t)(rb + r) * VOCAB + v] = acc[r] + bb;
}

extern "C" void kernel_launch(void* const* d_in, const int* in_sizes, int n_in,
                              void* d_out, int out_size, void* d_ws, size_t ws_size,
                              hipStream_t stream) {
    (void)in_sizes; (void)n_in; (void)out_size; (void)ws_size;
    const int*   tok      = (const int*)  d_in[0];
    const float* embed    = (const float*)d_in[1];
    const float* ln1_g    = (const float*)d_in[2];
    const float* ln2_g    = (const float*)d_in[3];
    const float* wq       = (const float*)d_in[4];
    const float* wk       = (const float*)d_in[5];
    const float* wv       = (const float*)d_in[6];
    const float* wo       = (const float*)d_in[7];
    const float* ffn_up   = (const float*)d_in[8];
    const float* ffn_down = (const float*)d_in[9];
    const float* rotor    = (const float*)d_in[10];
    const float* mixw     = (const float*)d_in[11];
    const float* out_ln_g = (const float*)d_in[12];
    const float* sel      = (const float*)d_in[13];
    const float* head_w   = (const float*)d_in[14];
    const float* head_b   = (const float*)d_in[15];
    float* out = (float*)d_out;

    float* ws  = (float*)d_ws;
    float* x    = ws;                 // 2,097,152
    float* xn   = x    + 2097152;     // 2,097,152
    float* q    = xn   + 2097152;
    float* k    = q    + 2097152;
    float* v    = k    + 2097152;
    float* o    = v    + 2097152;
    float* h    = o    + 2097152;     // 8,388,608
    float* Tmx  = h    + 8388608;     // 512
    float* g0   = Tmx  + 512;         // 131,072
    float* hwT  = g0   + 131072;      // 2,048,000

    embed_pe_kernel<<<(BATCH * SEQ * NC + 255) / 256, 256, 0, stream>>>(tok, embed, x);
    tmix_kernel<<<NLAY, 256, 0, stream>>>(rotor, mixw, Tmx);
    transpose_hw<<<(VOCAB * NC + 255) / 256, 256, 0, stream>>>(head_w, hwT);

    for (int l = 0; l < NLAY; l++) {
        cln_kernel<<<BATCH * SEQ, 256, 0, stream>>>(x, ln1_g + l * NC, xn);
        qkv_kernel<<<BATCH * SEQ, 256, 0, stream>>>(xn, wq + l * NC * NC, wk + l * NC * NC,
                                                    wv + l * NC * NC, q, k, v);
        dim3 ag(16, BATCH * NH);
        flash_attn_kernel<<<ag, 256, 0, stream>>>(q, k, v, o);
        proj_add_kernel<<<BATCH * SEQ, 256, 0, stream>>>(o, wo + l * NC * NC, x);
        cln_kernel<<<BATCH * SEQ, 256, 0, stream>>>(x, ln2_g + l * NC, xn);
        ffn_up_gelu_kernel<<<BATCH * SEQ, 256, 0, stream>>>(xn, ffn_up + l * CEXP * NC,
                                                            Tmx + l * 256, h);
        ffn_down_kernel<<<BATCH * SEQ, 256, 0, stream>>>(h, ffn_down + l * NC * CEXP, x);
    }

    g0_kernel<<<BATCH * SEQ, 256, 0, stream>>>(x, out_ln_g, sel, g0);
    dim3 hg(VOCAB / 256, BATCH * SEQ / 32);
    head_kernel<<<hg, 256, 0, stream>>>(g0, hwT, head_b, out);
}